// Round 1
// baseline (23220.557 us; speedup 1.0000x reference)
//
#include <hip/hip_runtime.h>
#include <cstddef>

#define Bn 256
#define Pn 192
#define Mn 321
#define HIDCn 128
#define HIDRn 128
#define HIDSn 8
#define CKn 6
#define SKIPn 24
#define HWn 24
#define Ln 187   // Pn - CKn + 1
#define PTn 7

__device__ __forceinline__ float sigmf(float x) { return 1.f / (1.f + expf(-x)); }
__device__ __forceinline__ unsigned short f2bf(float v) { return (unsigned short)(__float_as_uint(v) >> 16); }
__device__ __forceinline__ float bf2f(unsigned short u) { return __uint_as_float(((unsigned)u) << 16); }

// ---------- transpose x (B,P,M) -> xT (B,M,P) ----------
__global__ __launch_bounds__(256) void transpose_k(const float* __restrict__ x, float* __restrict__ xT) {
  __shared__ float t[32][33];
  int b = blockIdx.x, m0 = blockIdx.y * 32, p0 = blockIdx.z * 32;
  int tx = threadIdx.x & 31, ty = threadIdx.x >> 5;
  const float* xb = x + (size_t)b * Pn * Mn;
  float* ob = xT + (size_t)b * Mn * Pn;
  for (int i = ty; i < 32; i += 8) {
    int p = p0 + i, m = m0 + tx;
    t[i][tx] = (p < Pn && m < Mn) ? xb[(size_t)p * Mn + m] : 0.f;
  }
  __syncthreads();
  for (int i = ty; i < 32; i += 8) {
    int m = m0 + i, p = p0 + tx;
    if (m < Mn && p < Pn) ob[(size_t)m * Pn + p] = t[tx][i];
  }
}

// ---------- deinterleave rows of length 2*Th -> e,o (length Th) ----------
__global__ __launch_bounds__(256) void deint_k(const float2* __restrict__ in, float* __restrict__ e,
                                               float* __restrict__ o, int n) {
  int i = blockIdx.x * 256 + threadIdx.x;
  if (i < n) { float2 v = in[i]; e[i] = v.x; o[i] = v.y; }
}

// ---------- zip e,o (length Th) -> out (length 2*Th) ----------
__global__ __launch_bounds__(256) void zip_k(const float* __restrict__ e, const float* __restrict__ o,
                                             float2* __restrict__ out, int n) {
  int i = blockIdx.x * 256 + threadIdx.x;
  if (i < n) out[i] = make_float2(e[i], o[i]);
}

// ---------- final zip + add x^T:  XR = zip(RL,RR) + xT ----------
__global__ __launch_bounds__(256) void zipaddx_k(const float* __restrict__ e, const float* __restrict__ o,
                                                 const float2* __restrict__ xt, float2* __restrict__ out, int n) {
  int i = blockIdx.x * 256 + threadIdx.x;
  if (i < n) { float2 v = xt[i]; out[i] = make_float2(e[i] + v.x, o[i] + v.y); }
}

// ---------- branch conv: in (B,M,Tin) -> dst (B,M,Tout) ----------
// MODE 0: leaky(y+b)  (K=5 path, replication pad 3)
// MODE 1: dst = src * exp(tanh(y+b))   MODE 2: dst = src + tanh(y+b)   MODE 3: dst = src - tanh(y+b)
template <int K, int MODE>
__global__ __launch_bounds__(128) void conv_branch(const float* __restrict__ in, int Tin,
                                                   const float* __restrict__ w,    // (M,M,K)
                                                   const float* __restrict__ bias, // (M)
                                                   const float* __restrict__ src,
                                                   float* __restrict__ dst, int Tout) {
  constexpr int TT = 16;
  constexpr int TW = TT + K - 1;
  constexpr int PADL = (K == 5) ? 3 : 0;
  __shared__ float sz[Mn * TW];
  int b = blockIdx.x;
  int co0 = blockIdx.y * 64;
  int t0 = blockIdx.z * TT;
  int tid = threadIdx.x;
  const float* inb = in + (size_t)b * Mn * Tin;
  for (int idx = tid; idx < Mn * TW; idx += 128) {
    int ci = idx / TW, jj = idx - ci * TW;
    int j = t0 + jj - PADL;
    j = max(0, min(j, Tin - 1));
    sz[idx] = inb[(size_t)ci * Tin + j];
  }
  __syncthreads();
  int co = co0 + (tid & 63);
  int tb = (tid >> 6) * 8;   // 2 t-groups of 8
  if (co >= Mn) return;
  const float* wrow = w + (size_t)co * Mn * K;
  float acc[8] = {0.f, 0.f, 0.f, 0.f, 0.f, 0.f, 0.f, 0.f};
  for (int ci = 0; ci < Mn; ++ci) {
    float wv[K];
#pragma unroll
    for (int k = 0; k < K; ++k) wv[k] = wrow[ci * K + k];
    float xv[8 + K - 1];
#pragma unroll
    for (int j = 0; j < 8 + K - 1; ++j) xv[j] = sz[ci * TW + tb + j];
#pragma unroll
    for (int tt = 0; tt < 8; ++tt)
#pragma unroll
      for (int k = 0; k < K; ++k) acc[tt] = fmaf(wv[k], xv[tt + k], acc[tt]);
  }
  float bb = bias[co];
  size_t obase = ((size_t)b * Mn + co) * Tout;
#pragma unroll
  for (int tt = 0; tt < 8; ++tt) {
    int t = t0 + tb + tt;
    if (t < Tout) {
      float y = acc[tt] + bb;
      float outv;
      if constexpr (MODE == 0) {
        outv = y > 0.f ? y : 0.01f * y;
      } else {
        float th = tanhf(y);
        float s = src[obase + t];
        if constexpr (MODE == 1) outv = s * expf(th);
        else if constexpr (MODE == 2) outv = s + th;
        else outv = s - th;
      }
      dst[obase + t] = outv;
    }
  }
}

// ---------- conv2d: XR (B,M,P) -> Cc (L,B,HIDC), relu ----------
__global__ __launch_bounds__(256) void conv2d_k(const float* __restrict__ xr, const float* __restrict__ w,
                                                const float* __restrict__ bias, float* __restrict__ out) {
  constexpr int LT = 16;
  constexpr int TW = LT + CKn - 1;  // 21
  __shared__ float sx[Mn * TW];
  int n = blockIdx.x;
  int i0 = blockIdx.y * 64;
  int l0 = blockIdx.z * LT;
  int tid = threadIdx.x;
  const float* xb = xr + (size_t)n * Mn * Pn;
  for (int idx = tid; idx < Mn * TW; idx += 256) {
    int m = idx / TW, jj = idx - m * TW;
    int p = min(l0 + jj, Pn - 1);
    sx[idx] = xb[(size_t)m * Pn + p];
  }
  __syncthreads();
  int i = i0 + (tid & 63);
  int lb = (tid >> 6) * 4;  // 4 l per thread
  float acc[4] = {0.f, 0.f, 0.f, 0.f};
  for (int m = 0; m < Mn; ++m) {
    float xv[4 + CKn - 1];
#pragma unroll
    for (int j = 0; j < 9; ++j) xv[j] = sx[m * TW + lb + j];
#pragma unroll
    for (int k = 0; k < CKn; ++k) {
      float wv = w[((size_t)i * CKn + k) * Mn + m];
#pragma unroll
      for (int tt = 0; tt < 4; ++tt) acc[tt] = fmaf(wv, xv[tt + k], acc[tt]);
    }
  }
  float bb = bias[i];
#pragma unroll
  for (int tt = 0; tt < 4; ++tt) {
    int l = l0 + lb + tt;
    if (l < Ln) {
      float y = acc[tt] + bb;
      out[((size_t)l * Bn + n) * HIDCn + i] = y > 0.f ? y : 0.f;
    }
  }
}

// ---------- GEMM: gi_all[r,g] = bih[g] + sum_k A[r,k]*W[g,k];  A=(47872,128), W=(384,128) ----------
__global__ __launch_bounds__(256) void gemm_gi(const float* __restrict__ A, const float* __restrict__ W,
                                               const float* __restrict__ bias, float* __restrict__ out) {
  __shared__ float sA[64][129];
  __shared__ float sB[64][129];
  int r0 = blockIdx.x * 64, c0 = blockIdx.y * 64;
  int tid = threadIdx.x;
  for (int idx = tid; idx < 64 * 128; idx += 256) {
    int r = idx >> 7, k = idx & 127;
    sA[r][k] = A[(size_t)(r0 + r) * 128 + k];
    sB[r][k] = W[(size_t)(c0 + r) * 128 + k];
  }
  __syncthreads();
  int tx = tid & 15, ty = tid >> 4;
  int rr = ty * 4, cc = tx * 4;
  float acc[4][4] = {};
  for (int k = 0; k < 128; ++k) {
    float a[4], bv[4];
#pragma unroll
    for (int u = 0; u < 4; ++u) a[u] = sA[rr + u][k];
#pragma unroll
    for (int v = 0; v < 4; ++v) bv[v] = sB[cc + v][k];
#pragma unroll
    for (int u = 0; u < 4; ++u)
#pragma unroll
      for (int v = 0; v < 4; ++v) acc[u][v] = fmaf(a[u], bv[v], acc[u][v]);
  }
#pragma unroll
  for (int u = 0; u < 4; ++u)
#pragma unroll
    for (int v = 0; v < 4; ++v)
      out[(size_t)(r0 + rr + u) * 384 + (c0 + cc + v)] = acc[u][v] + bias[c0 + cc + v];
}

// ---------- GRU1 recurrent part: gi (187,256,384) -> h (256,128); 2 rows per block ----------
__global__ __launch_bounds__(384) void gru1_k(const float* __restrict__ gi, const float* __restrict__ whh,
                                              const float* __restrict__ bhh, float* __restrict__ hout) {
  __shared__ unsigned short swhh[384 * 130];  // bf16, padded stride vs bank conflicts
  __shared__ float hs[2][128];
  __shared__ float ghb[384][2];
  int n0 = blockIdx.x * 2;
  int tid = threadIdx.x;
  for (int idx = tid; idx < 384 * 128; idx += 384) {
    int r = idx >> 7, i2 = idx & 127;
    swhh[r * 130 + i2] = f2bf(whh[idx]);
  }
  if (tid < 256) hs[tid >> 7][tid & 127] = 0.f;
  float bias_g = bhh[tid];
  __syncthreads();
  int r = tid >> 7, j = tid & 127;
  for (int t = 0; t < Ln; ++t) {
    float g0 = bias_g, g1 = bias_g;
    const unsigned short* wr = swhh + tid * 130;
    for (int i = 0; i < 128; ++i) {
      float wv = bf2f(wr[i]);
      g0 = fmaf(wv, hs[0][i], g0);
      g1 = fmaf(wv, hs[1][i], g1);
    }
    ghb[tid][0] = g0;
    ghb[tid][1] = g1;
    __syncthreads();
    float hnew = 0.f;
    if (tid < 256) {
      const float* girow = gi + ((size_t)t * Bn + (n0 + r)) * 384;
      float gir = girow[j], giz = girow[128 + j], gin = girow[256 + j];
      float hr = ghb[j][r], hz = ghb[128 + j][r], hn = ghb[256 + j][r];
      float rg = sigmf(gir + hr);
      float zg = sigmf(giz + hz);
      float ng = tanhf(gin + rg * hn);
      hnew = (1.f - zg) * ng + zg * hs[r][j];
    }
    // writes own slot; all cross-thread reads of hs happened before the previous barrier
    if (tid < 256) hs[r][j] = hnew;
    __syncthreads();
  }
  if (tid < 256) hout[(size_t)(n0 + r) * 128 + j] = hs[r][j];
}

// ---------- skip-GRU input gemm: gi_s (7,6144,24) ----------
__global__ __launch_bounds__(256) void gis_k(const float* __restrict__ cc, const float* __restrict__ wih,
                                             const float* __restrict__ bih, float* __restrict__ gi) {
  __shared__ float sx[24 * 128];
  int t = blockIdx.x, b = blockIdx.y;
  int tid = threadIdx.x;
  for (int idx = tid; idx < 24 * 128; idx += 256) {
    int sk = idx >> 7, i = idx & 127;
    int l = 19 + t * 24 + sk;
    sx[idx] = cc[((size_t)l * Bn + b) * HIDCn + i];
  }
  __syncthreads();
  for (int idx = tid; idx < 576; idx += 256) {
    int sk = idx / 24, g = idx - sk * 24;
    float a = bih[g];
    for (int i = 0; i < 128; ++i) a = fmaf(sx[sk * 128 + i], wih[g * 128 + i], a);
    gi[((size_t)t * (Bn * SKIPn) + b * 24 + sk) * 24 + g] = a;
  }
}

// ---------- skip-GRU recurrent: one thread per row ----------
__global__ __launch_bounds__(256) void grus_k(const float* __restrict__ gi, const float* __restrict__ whh,
                                              const float* __restrict__ bhh, float* __restrict__ hout) {
  __shared__ float sw[24 * 8];
  __shared__ float sb[24];
  int tid = threadIdx.x;
  int n = blockIdx.x * 256 + tid;
  if (tid < 192) sw[tid] = whh[tid];
  if (tid < 24) sb[tid] = bhh[tid];
  __syncthreads();
  float h[8];
#pragma unroll
  for (int jj = 0; jj < 8; ++jj) h[jj] = 0.f;
  for (int t = 0; t < PTn; ++t) {
    const float* gir = gi + ((size_t)t * (Bn * SKIPn) + n) * 24;
    float gh[24];
#pragma unroll
    for (int g = 0; g < 24; ++g) {
      float a = sb[g];
#pragma unroll
      for (int jj = 0; jj < 8; ++jj) a = fmaf(sw[g * 8 + jj], h[jj], a);
      gh[g] = a;
    }
#pragma unroll
    for (int jj = 0; jj < 8; ++jj) {
      float rg = sigmf(gir[jj] + gh[jj]);
      float zg = sigmf(gir[8 + jj] + gh[8 + jj]);
      float ng = tanhf(gir[16 + jj] + rg * gh[16 + jj]);
      h[jj] = (1.f - zg) * ng + zg * h[jj];
    }
  }
#pragma unroll
  for (int jj = 0; jj < 8; ++jj) hout[(size_t)n * 8 + jj] = h[jj];
}

// ---------- final: out = [h1,hs] @ lin1^T + lin1_b + highway ----------
__global__ __launch_bounds__(384) void final_k(const float* __restrict__ h1, const float* __restrict__ hsb,
                                               const float* __restrict__ lw, const float* __restrict__ lb,
                                               const float* __restrict__ xr, const float* __restrict__ hww,
                                               const float* __restrict__ hwb, float* __restrict__ out) {
  __shared__ float sr[320];
  __shared__ float shw[24];
  int b = blockIdx.x;
  int tid = threadIdx.x;
  if (tid < 128) sr[tid] = h1[(size_t)b * 128 + tid];
  else if (tid < 320) sr[tid] = hsb[(size_t)b * 192 + (tid - 128)];
  if (tid >= 320 && tid < 344) shw[tid - 320] = hww[tid - 320];
  __syncthreads();
  int m = tid;
  if (m >= Mn) return;
  float a = lb[m];
  const float* wr = lw + (size_t)m * 320;
  for (int c = 0; c < 320; ++c) a = fmaf(sr[c], wr[c], a);
  float z = hwb[0];
  const float* xrr = xr + ((size_t)b * Mn + m) * Pn + (Pn - HWn);
#pragma unroll
  for (int k = 0; k < HWn; ++k) z = fmaf(xrr[k], shw[k], z);
  out[(size_t)b * Mn + m] = a + z;
}

extern "C" void kernel_launch(void* const* d_in, const int* in_sizes, int n_in,
                              void* d_out, int out_size, void* d_ws, size_t ws_size,
                              hipStream_t stream) {
  const float* x = (const float*)d_in[0];
  const float* tw1 = (const float*)d_in[1];
  const float* tb1 = (const float*)d_in[2];
  const float* tw2 = (const float*)d_in[3];
  const float* tb2 = (const float*)d_in[4];
  const float* c1w = (const float*)d_in[5];
  const float* c1b = (const float*)d_in[6];
  const float* g1wih = (const float*)d_in[7];
  const float* g1whh = (const float*)d_in[8];
  const float* g1bih = (const float*)d_in[9];
  const float* g1bhh = (const float*)d_in[10];
  const float* gswih = (const float*)d_in[11];
  const float* gswhh = (const float*)d_in[12];
  const float* gsbih = (const float*)d_in[13];
  const float* gsbhh = (const float*)d_in[14];
  const float* l1w = (const float*)d_in[15];
  const float* l1b = (const float*)d_in[16];
  const float* hww = (const float*)d_in[17];
  const float* hwb = (const float*)d_in[18];
  float* out = (float*)d_out;

  const size_t SZ24 = (size_t)Bn * Mn * 24, SZ26 = (size_t)Bn * Mn * 26;
  const size_t SZ48 = (size_t)Bn * Mn * 48, SZ50 = (size_t)Bn * Mn * 50;
  const size_t RSZ = 2 * (SZ24 + SZ26);  // 8,217,600 floats: fits 2x(S48), 2x(S50), 2x(S24+S26), S98
  float* pool = (float*)d_ws;
  float* R0 = pool;
  float* R1 = pool + RSZ;
  float* R2 = pool + 2 * RSZ;
  float* R3 = pool + 3 * RSZ;
  float* R5 = pool + 4 * RSZ;                       // xT during tree, then gi_all
  const size_t GI_SZ = (size_t)Ln * Bn * 384;       // 18,382,848
  float* R6 = R5 + GI_SZ;
  float* h1 = R6;
  float* hsb = R6 + (size_t)Bn * HIDRn;
  float* gis = hsb + (size_t)Bn * SKIPn * HIDSn;

  float* xT = R5;
  float* XR = R2;  // spans into R3 (B*M*192 floats)
  float* Cc = R0;

  auto node = [&](int ni, const float* in, float* E, float* O, float* T1, float* T2, int Th) {
    int n = Bn * Mn * Th;
    deint_k<<<dim3((n + 255) / 256), 256, 0, stream>>>((const float2*)in, E, O, n);
    int To5 = Th + 2;
    dim3 g5(Bn, (Mn + 63) / 64, (To5 + 15) / 16), g3(Bn, (Mn + 63) / 64, (Th + 15) / 16);
    const float *W1[4], *Bb1[4], *W2[4], *Bb2[4];
    for (int j = 0; j < 4; ++j) {
      W1[j] = tw1 + (size_t)(ni * 4 + j) * Mn * Mn * 5;
      Bb1[j] = tb1 + (size_t)(ni * 4 + j) * Mn;
      W2[j] = tw2 + (size_t)(ni * 4 + j) * Mn * Mn * 3;
      Bb2[j] = tb2 + (size_t)(ni * 4 + j) * Mn;
    }
    conv_branch<5, 0><<<g5, 128, 0, stream>>>(E, Th, W1[0], Bb1[0], nullptr, T1, To5);
    conv_branch<5, 0><<<g5, 128, 0, stream>>>(O, Th, W1[1], Bb1[1], nullptr, T2, To5);
    conv_branch<3, 1><<<g3, 128, 0, stream>>>(T2, To5, W2[1], Bb2[1], E, E, Th);  // c = e*exp(branch(o))
    conv_branch<3, 1><<<g3, 128, 0, stream>>>(T1, To5, W2[0], Bb2[0], O, O, Th);  // d = o*exp(branch(e))
    conv_branch<5, 0><<<g5, 128, 0, stream>>>(O, Th, W1[2], Bb1[2], nullptr, T1, To5);
    conv_branch<5, 0><<<g5, 128, 0, stream>>>(E, Th, W1[3], Bb1[3], nullptr, T2, To5);
    conv_branch<3, 2><<<g3, 128, 0, stream>>>(T1, To5, W2[2], Bb2[2], E, E, Th);  // eu = c + branch(d)
    conv_branch<3, 3><<<g3, 128, 0, stream>>>(T2, To5, W2[3], Bb2[3], O, O, Th);  // ou = d - branch(c)
  };
  auto zip = [&](const float* e, const float* o, float* dst, int Th) {
    int n = Bn * Mn * Th;
    zip_k<<<dim3((n + 255) / 256), 256, 0, stream>>>(e, o, (float2*)dst, n);
  };

  transpose_k<<<dim3(Bn, (Mn + 31) / 32, (Pn + 31) / 32), 256, 0, stream>>>(x, xT);

  node(0, xT, R0, R1, R2, R3, 96);                                       // eu0=R0, ou0=R1
  node(1, R0, R2, R2 + SZ48, R3, R3 + SZ50, 48);                         // eu1/ou1 in R2
  node(2, R2, R0, R0 + SZ24, R0 + 2 * SZ24, R0 + 2 * SZ24 + SZ26, 24);   // leaf on eu1
  zip(R0, R0 + SZ24, R2, 24);                                            // L2 -> R2[0:SZ48]
  node(3, R2 + SZ48, R0, R0 + SZ24, R0 + 2 * SZ24, R0 + 2 * SZ24 + SZ26, 24);
  zip(R0, R0 + SZ24, R2 + SZ48, 24);                                     // L3 -> R2[SZ48:]
  zip(R2, R2 + SZ48, R0, 48);                                            // RL -> R0
  node(4, R1, R2, R2 + SZ48, R3, R3 + SZ50, 48);                         // eu4/ou4 in R2
  node(5, R2, R1, R1 + SZ24, R1 + 2 * SZ24, R1 + 2 * SZ24 + SZ26, 24);
  zip(R1, R1 + SZ24, R2, 24);                                            // L5 -> R2[0:SZ48]
  node(6, R2 + SZ48, R1, R1 + SZ24, R1 + 2 * SZ24, R1 + 2 * SZ24 + SZ26, 24);
  zip(R1, R1 + SZ24, R2 + SZ48, 24);                                     // L6 -> R2[SZ48:]
  zip(R2, R2 + SZ48, R1, 48);                                            // RR -> R1
  {
    int n = Bn * Mn * 96;
    zipaddx_k<<<dim3((n + 255) / 256), 256, 0, stream>>>(R0, R1, (const float2*)xT, (float2*)XR, n);
  }

  conv2d_k<<<dim3(Bn, 2, (Ln + 15) / 16), 256, 0, stream>>>(XR, c1w, c1b, Cc);
  gemm_gi<<<dim3((Ln * Bn) / 64, 384 / 64), 256, 0, stream>>>(Cc, g1wih, g1bih, R5);
  gru1_k<<<dim3(Bn / 2), 384, 0, stream>>>(R5, g1whh, g1bhh, h1);
  gis_k<<<dim3(PTn, Bn), 256, 0, stream>>>(Cc, gswih, gsbih, gis);
  grus_k<<<dim3((Bn * SKIPn) / 256), 256, 0, stream>>>(gis, gswhh, gsbhh, hsb);
  final_k<<<dim3(Bn), 384, 0, stream>>>(h1, hsb, l1w, l1b, XR, hww, hwb, out);
}

// Round 2
// 18026.259 us; speedup vs baseline: 1.2882x; 1.2882x over previous
//
#include <hip/hip_runtime.h>
#include <cstddef>

#define Bn 256
#define Pn 192
#define Mn 321
#define HIDCn 128
#define HIDRn 128
#define HIDSn 8
#define CKn 6
#define SKIPn 24
#define HWn 24
#define Ln 187   // Pn - CKn + 1
#define PTn 7

typedef unsigned short ushort_t;

__device__ __forceinline__ float sigmf(float x) { return 1.f / (1.f + expf(-x)); }
__device__ __forceinline__ unsigned short f2bf(float v) { return (unsigned short)(__float_as_uint(v) >> 16); }
__device__ __forceinline__ unsigned short f2bf_rne(float v) {
  unsigned u = __float_as_uint(v);
  unsigned r = (u + 0x7FFFu + ((u >> 16) & 1u)) >> 16;
  return (unsigned short)r;
}
__device__ __forceinline__ float bf2f(unsigned short u) { return __uint_as_float(((unsigned)u) << 16); }

__device__ __forceinline__ void cstore(float* p, float v) { *p = v; }
__device__ __forceinline__ void cstore(unsigned short* p, float v) { *p = f2bf_rne(v); }

// ---------- generic tiled transpose repack: per g, (rows x cols) -> (cols x rows) ----------
template <typename OutT>
__global__ __launch_bounds__(256) void repack_t(const float* __restrict__ in, OutT* __restrict__ out,
                                                int rows, int cols, size_t gstride) {
  __shared__ float t[32][33];
  int r0 = blockIdx.x * 32, c0 = blockIdx.y * 32;
  const float* ig = in + (size_t)blockIdx.z * gstride;
  OutT* og = out + (size_t)blockIdx.z * gstride;
  int tx = threadIdx.x & 31, ty = threadIdx.x >> 5;
  for (int i = ty; i < 32; i += 8) {
    int r = r0 + i, c = c0 + tx;
    t[i][tx] = (r < rows && c < cols) ? ig[(size_t)r * cols + c] : 0.f;
  }
  __syncthreads();
  for (int i = ty; i < 32; i += 8) {
    int c = c0 + i, r = r0 + tx;
    if (c < cols && r < rows) cstore(&og[(size_t)c * rows + r], t[tx][i]);
  }
}

// ---------- transpose x (B,P,M) -> xT (B,M,P) ----------
__global__ __launch_bounds__(256) void transpose_k(const float* __restrict__ x, float* __restrict__ xT) {
  __shared__ float t[32][33];
  int b = blockIdx.x, m0 = blockIdx.y * 32, p0 = blockIdx.z * 32;
  int tx = threadIdx.x & 31, ty = threadIdx.x >> 5;
  const float* xb = x + (size_t)b * Pn * Mn;
  float* ob = xT + (size_t)b * Mn * Pn;
  for (int i = ty; i < 32; i += 8) {
    int p = p0 + i, m = m0 + tx;
    t[i][tx] = (p < Pn && m < Mn) ? xb[(size_t)p * Mn + m] : 0.f;
  }
  __syncthreads();
  for (int i = ty; i < 32; i += 8) {
    int m = m0 + i, p = p0 + tx;
    if (m < Mn && p < Pn) ob[(size_t)m * Pn + p] = t[tx][i];
  }
}

// ---------- deinterleave rows of length 2*Th -> e,o (length Th) ----------
__global__ __launch_bounds__(256) void deint_k(const float2* __restrict__ in, float* __restrict__ e,
                                               float* __restrict__ o, int n) {
  int i = blockIdx.x * 256 + threadIdx.x;
  if (i < n) { float2 v = in[i]; e[i] = v.x; o[i] = v.y; }
}

// ---------- zip e,o (length Th) -> out (length 2*Th) ----------
__global__ __launch_bounds__(256) void zip_k(const float* __restrict__ e, const float* __restrict__ o,
                                             float2* __restrict__ out, int n) {
  int i = blockIdx.x * 256 + threadIdx.x;
  if (i < n) out[i] = make_float2(e[i], o[i]);
}

// ---------- final zip + add x^T:  XR = zip(RL,RR) + xT ----------
__global__ __launch_bounds__(256) void zipaddx_k(const float* __restrict__ e, const float* __restrict__ o,
                                                 const float2* __restrict__ xt, float2* __restrict__ out, int n) {
  int i = blockIdx.x * 256 + threadIdx.x;
  if (i < n) { float2 v = xt[i]; out[i] = make_float2(e[i] + v.x, o[i] + v.y); }
}

// ---------- branch conv: in (B,M,Tin) -> dst (B,M,Tout) ----------
// weights repacked bf16: (ci, K, co) so lanes (co) read contiguous.
// MODE 0: leaky(y+b)  (K=5 path, replication pad 3)
// MODE 1: dst = src * exp(tanh(y+b))   MODE 2: dst = src + tanh(y+b)   MODE 3: dst = src - tanh(y+b)
template <int K, int MODE>
__global__ __launch_bounds__(128) void conv_branch(const float* __restrict__ in, int Tin,
                                                   const unsigned short* __restrict__ wr,  // (M,K,M) bf16
                                                   const float* __restrict__ bias,         // (M)
                                                   const float* __restrict__ src,
                                                   float* __restrict__ dst, int Tout) {
  constexpr int TT = 16;
  constexpr int TW = TT + K - 1;
  constexpr int PADL = (K == 5) ? 3 : 0;
  __shared__ float sz[Mn * TW];
  int b = blockIdx.x;
  int co0 = blockIdx.y * 64;
  int t0 = blockIdx.z * TT;
  int tid = threadIdx.x;
  const float* inb = in + (size_t)b * Mn * Tin;
  for (int idx = tid; idx < Mn * TW; idx += 128) {
    int ci = idx / TW, jj = idx - ci * TW;
    int j = t0 + jj - PADL;
    j = max(0, min(j, Tin - 1));
    sz[idx] = inb[(size_t)ci * Tin + j];
  }
  __syncthreads();
  int co = co0 + (tid & 63);
  int tb = (tid >> 6) * 8;   // 2 t-groups of 8
  if (co >= Mn) return;
  const unsigned short* wbase = wr + co;
  float acc[8] = {0.f, 0.f, 0.f, 0.f, 0.f, 0.f, 0.f, 0.f};
  for (int ci = 0; ci < Mn; ++ci) {
    float wv[K];
#pragma unroll
    for (int k = 0; k < K; ++k) wv[k] = bf2f(wbase[(size_t)(ci * K + k) * Mn]);
    float xv[8 + K - 1];
#pragma unroll
    for (int j = 0; j < 8 + K - 1; ++j) xv[j] = sz[ci * TW + tb + j];
#pragma unroll
    for (int tt = 0; tt < 8; ++tt)
#pragma unroll
      for (int k = 0; k < K; ++k) acc[tt] = fmaf(wv[k], xv[tt + k], acc[tt]);
  }
  float bb = bias[co];
  size_t obase = ((size_t)b * Mn + co) * Tout;
#pragma unroll
  for (int tt = 0; tt < 8; ++tt) {
    int t = t0 + tb + tt;
    if (t < Tout) {
      float y = acc[tt] + bb;
      float outv;
      if constexpr (MODE == 0) {
        outv = y > 0.f ? y : 0.01f * y;
      } else {
        float th = tanhf(y);
        float s = src[obase + t];
        if constexpr (MODE == 1) outv = s * expf(th);
        else if constexpr (MODE == 2) outv = s + th;
        else outv = s - th;
      }
      dst[obase + t] = outv;
    }
  }
}

// ---------- conv2d: XR (B,M,P) -> Cc (L,B,HIDC), relu; weights repacked (k,m,i) fp32 ----------
__global__ __launch_bounds__(256) void conv2d_k(const float* __restrict__ xr, const float* __restrict__ wT,
                                                const float* __restrict__ bias, float* __restrict__ out) {
  constexpr int LT = 16;
  constexpr int TW = LT + CKn - 1;  // 21
  __shared__ float sx[Mn * TW];
  int n = blockIdx.x;
  int i0 = blockIdx.y * 64;
  int l0 = blockIdx.z * LT;
  int tid = threadIdx.x;
  const float* xb = xr + (size_t)n * Mn * Pn;
  for (int idx = tid; idx < Mn * TW; idx += 256) {
    int m = idx / TW, jj = idx - m * TW;
    int p = min(l0 + jj, Pn - 1);
    sx[idx] = xb[(size_t)m * Pn + p];
  }
  __syncthreads();
  int i = i0 + (tid & 63);
  int lb = (tid >> 6) * 4;  // 4 l per thread
  float acc[4] = {0.f, 0.f, 0.f, 0.f};
  for (int m = 0; m < Mn; ++m) {
    float xv[4 + CKn - 1];
#pragma unroll
    for (int j = 0; j < 9; ++j) xv[j] = sx[m * TW + lb + j];
#pragma unroll
    for (int k = 0; k < CKn; ++k) {
      float wv = wT[(size_t)(k * Mn + m) * HIDCn + i];
#pragma unroll
      for (int tt = 0; tt < 4; ++tt) acc[tt] = fmaf(wv, xv[tt + k], acc[tt]);
    }
  }
  float bb = bias[i];
#pragma unroll
  for (int tt = 0; tt < 4; ++tt) {
    int l = l0 + lb + tt;
    if (l < Ln) {
      float y = acc[tt] + bb;
      out[((size_t)l * Bn + n) * HIDCn + i] = y > 0.f ? y : 0.f;
    }
  }
}

// ---------- GEMM: gi_all[r,g] = bih[g] + sum_k A[r,k]*W[g,k];  A=(47872,128), W=(384,128) ----------
__global__ __launch_bounds__(256) void gemm_gi(const float* __restrict__ A, const float* __restrict__ W,
                                               const float* __restrict__ bias, float* __restrict__ out) {
  __shared__ float sA[64][129];
  __shared__ float sB[64][129];
  int r0 = blockIdx.x * 64, c0 = blockIdx.y * 64;
  int tid = threadIdx.x;
  for (int idx = tid; idx < 64 * 128; idx += 256) {
    int r = idx >> 7, k = idx & 127;
    sA[r][k] = A[(size_t)(r0 + r) * 128 + k];
    sB[r][k] = W[(size_t)(c0 + r) * 128 + k];
  }
  __syncthreads();
  int tx = tid & 15, ty = tid >> 4;
  int rr = ty * 4, cc = tx * 4;
  float acc[4][4] = {};
  for (int k = 0; k < 128; ++k) {
    float a[4], bv[4];
#pragma unroll
    for (int u = 0; u < 4; ++u) a[u] = sA[rr + u][k];
#pragma unroll
    for (int v = 0; v < 4; ++v) bv[v] = sB[cc + v][k];
#pragma unroll
    for (int u = 0; u < 4; ++u)
#pragma unroll
      for (int v = 0; v < 4; ++v) acc[u][v] = fmaf(a[u], bv[v], acc[u][v]);
  }
#pragma unroll
  for (int u = 0; u < 4; ++u)
#pragma unroll
    for (int v = 0; v < 4; ++v)
      out[(size_t)(r0 + rr + u) * 384 + (c0 + cc + v)] = acc[u][v] + bias[c0 + cc + v];
}

// ---------- GRU1 recurrent part: gi (187,256,384) -> h (256,128); 2 rows per block ----------
__global__ __launch_bounds__(384) void gru1_k(const float* __restrict__ gi, const float* __restrict__ whh,
                                              const float* __restrict__ bhh, float* __restrict__ hout) {
  __shared__ unsigned short swhh[384 * 130];  // bf16, padded stride vs bank conflicts
  __shared__ float hs[2][128];
  __shared__ float ghb[384][2];
  int n0 = blockIdx.x * 2;
  int tid = threadIdx.x;
  for (int idx = tid; idx < 384 * 128; idx += 384) {
    int r = idx >> 7, i2 = idx & 127;
    swhh[r * 130 + i2] = f2bf(whh[idx]);
  }
  if (tid < 256) hs[tid >> 7][tid & 127] = 0.f;
  float bias_g = bhh[tid];
  __syncthreads();
  int r = tid >> 7, j = tid & 127;
  for (int t = 0; t < Ln; ++t) {
    float g0 = bias_g, g1 = bias_g;
    const unsigned short* wr = swhh + tid * 130;
    for (int i = 0; i < 128; ++i) {
      float wv = bf2f(wr[i]);
      g0 = fmaf(wv, hs[0][i], g0);
      g1 = fmaf(wv, hs[1][i], g1);
    }
    ghb[tid][0] = g0;
    ghb[tid][1] = g1;
    __syncthreads();
    float hnew = 0.f;
    if (tid < 256) {
      const float* girow = gi + ((size_t)t * Bn + (n0 + r)) * 384;
      float gir = girow[j], giz = girow[128 + j], gin = girow[256 + j];
      float hr = ghb[j][r], hz = ghb[128 + j][r], hn = ghb[256 + j][r];
      float rg = sigmf(gir + hr);
      float zg = sigmf(giz + hz);
      float ng = tanhf(gin + rg * hn);
      hnew = (1.f - zg) * ng + zg * hs[r][j];
    }
    if (tid < 256) hs[r][j] = hnew;
    __syncthreads();
  }
  if (tid < 256) hout[(size_t)(n0 + r) * 128 + j] = hs[r][j];
}

// ---------- skip-GRU input gemm: gi_s (7,6144,24) ----------
__global__ __launch_bounds__(256) void gis_k(const float* __restrict__ cc, const float* __restrict__ wih,
                                             const float* __restrict__ bih, float* __restrict__ gi) {
  __shared__ float sx[24 * 128];
  int t = blockIdx.x, b = blockIdx.y;
  int tid = threadIdx.x;
  for (int idx = tid; idx < 24 * 128; idx += 256) {
    int sk = idx >> 7, i = idx & 127;
    int l = 19 + t * 24 + sk;
    sx[idx] = cc[((size_t)l * Bn + b) * HIDCn + i];
  }
  __syncthreads();
  for (int idx = tid; idx < 576; idx += 256) {
    int sk = idx / 24, g = idx - sk * 24;
    float a = bih[g];
    for (int i = 0; i < 128; ++i) a = fmaf(sx[sk * 128 + i], wih[g * 128 + i], a);
    gi[((size_t)t * (Bn * SKIPn) + b * 24 + sk) * 24 + g] = a;
  }
}

// ---------- skip-GRU recurrent: one thread per row ----------
__global__ __launch_bounds__(256) void grus_k(const float* __restrict__ gi, const float* __restrict__ whh,
                                              const float* __restrict__ bhh, float* __restrict__ hout) {
  __shared__ float sw[24 * 8];
  __shared__ float sb[24];
  int tid = threadIdx.x;
  int n = blockIdx.x * 256 + tid;
  if (tid < 192) sw[tid] = whh[tid];
  if (tid < 24) sb[tid] = bhh[tid];
  __syncthreads();
  float h[8];
#pragma unroll
  for (int jj = 0; jj < 8; ++jj) h[jj] = 0.f;
  for (int t = 0; t < PTn; ++t) {
    const float* gir = gi + ((size_t)t * (Bn * SKIPn) + n) * 24;
    float gh[24];
#pragma unroll
    for (int g = 0; g < 24; ++g) {
      float a = sb[g];
#pragma unroll
      for (int jj = 0; jj < 8; ++jj) a = fmaf(sw[g * 8 + jj], h[jj], a);
      gh[g] = a;
    }
#pragma unroll
    for (int jj = 0; jj < 8; ++jj) {
      float rg = sigmf(gir[jj] + gh[jj]);
      float zg = sigmf(gir[8 + jj] + gh[8 + jj]);
      float ng = tanhf(gir[16 + jj] + rg * gh[16 + jj]);
      h[jj] = (1.f - zg) * ng + zg * h[jj];
    }
  }
#pragma unroll
  for (int jj = 0; jj < 8; ++jj) hout[(size_t)n * 8 + jj] = h[jj];
}

// ---------- final: out = [h1,hs] @ lin1^T + lin1_b + highway ----------
__global__ __launch_bounds__(384) void final_k(const float* __restrict__ h1, const float* __restrict__ hsb,
                                               const float* __restrict__ lw, const float* __restrict__ lb,
                                               const float* __restrict__ xr, const float* __restrict__ hww,
                                               const float* __restrict__ hwb, float* __restrict__ out) {
  __shared__ float sr[320];
  __shared__ float shw[24];
  int b = blockIdx.x;
  int tid = threadIdx.x;
  if (tid < 128) sr[tid] = h1[(size_t)b * 128 + tid];
  else if (tid < 320) sr[tid] = hsb[(size_t)b * 192 + (tid - 128)];
  if (tid >= 320 && tid < 344) shw[tid - 320] = hww[tid - 320];
  __syncthreads();
  int m = tid;
  if (m >= Mn) return;
  float a = lb[m];
  const float* wr = lw + (size_t)m * 320;
  for (int c = 0; c < 320; ++c) a = fmaf(sr[c], wr[c], a);
  float z = hwb[0];
  const float* xrr = xr + ((size_t)b * Mn + m) * Pn + (Pn - HWn);
#pragma unroll
  for (int k = 0; k < HWn; ++k) z = fmaf(xrr[k], shw[k], z);
  out[(size_t)b * Mn + m] = a + z;
}

extern "C" void kernel_launch(void* const* d_in, const int* in_sizes, int n_in,
                              void* d_out, int out_size, void* d_ws, size_t ws_size,
                              hipStream_t stream) {
  const float* x = (const float*)d_in[0];
  const float* tw1 = (const float*)d_in[1];
  const float* tb1 = (const float*)d_in[2];
  const float* tw2 = (const float*)d_in[3];
  const float* tb2 = (const float*)d_in[4];
  const float* c1w = (const float*)d_in[5];
  const float* c1b = (const float*)d_in[6];
  const float* g1wih = (const float*)d_in[7];
  const float* g1whh = (const float*)d_in[8];
  const float* g1bih = (const float*)d_in[9];
  const float* g1bhh = (const float*)d_in[10];
  const float* gswih = (const float*)d_in[11];
  const float* gswhh = (const float*)d_in[12];
  const float* gsbih = (const float*)d_in[13];
  const float* gsbhh = (const float*)d_in[14];
  const float* l1w = (const float*)d_in[15];
  const float* l1b = (const float*)d_in[16];
  const float* hww = (const float*)d_in[17];
  const float* hwb = (const float*)d_in[18];
  float* out = (float*)d_out;

  const size_t SZ24 = (size_t)Bn * Mn * 24, SZ26 = (size_t)Bn * Mn * 26;
  const size_t SZ48 = (size_t)Bn * Mn * 48, SZ50 = (size_t)Bn * Mn * 50;
  const size_t RSZ = 2 * (SZ24 + SZ26);  // 8,217,600 floats per region
  float* pool = (float*)d_ws;
  float* R0 = pool;
  float* R1 = pool + RSZ;
  float* R2 = pool + 2 * RSZ;
  float* R3 = pool + 3 * RSZ;
  float* R5 = pool + 4 * RSZ;                       // xT during tree, then gi_all
  const size_t GI_SZ = (size_t)Ln * Bn * 384;       // 18,382,848
  float* R6 = R5 + GI_SZ;
  float* h1 = R6;
  float* hsb = R6 + (size_t)Bn * HIDRn;
  float* gis = hsb + (size_t)Bn * SKIPn * HIDSn;
  float* wend = gis + (size_t)PTn * Bn * SKIPn * 24;
  // repacked weights (bf16 for tree, fp32 for conv2d)
  unsigned short* w1r = (unsigned short*)wend;                    // 28*321*1605 ushorts
  const size_t W1N = (size_t)28 * 321 * 1605;                     // 14,465,340
  unsigned short* w2r = w1r + W1N;                                // 28*321*963 ushorts
  const size_t W2N = (size_t)28 * 321 * 963;                      // 8,679,204
  float* c1wr = (float*)(w2r + W2N + (W2N & 1));                  // 128*1926 floats

  float* xT = R5;
  float* XR = R2;  // spans into R3 (B*M*192 floats)
  float* Cc = R0;

  // ---- weight repacks (every call; no persistent state allowed) ----
  {
    dim3 g1((321 + 31) / 32, (1605 + 31) / 32, 28);
    repack_t<unsigned short><<<g1, 256, 0, stream>>>(tw1, w1r, 321, 1605, (size_t)321 * 1605);
    dim3 g2((321 + 31) / 32, (963 + 31) / 32, 28);
    repack_t<unsigned short><<<g2, 256, 0, stream>>>(tw2, w2r, 321, 963, (size_t)321 * 963);
    dim3 g3((128 + 31) / 32, (1926 + 31) / 32, 1);
    repack_t<float><<<g3, 256, 0, stream>>>(c1w, c1wr, 128, 1926, (size_t)128 * 1926);
  }

  auto node = [&](int ni, const float* in, float* E, float* O, float* T1, float* T2, int Th) {
    int n = Bn * Mn * Th;
    deint_k<<<dim3((n + 255) / 256), 256, 0, stream>>>((const float2*)in, E, O, n);
    int To5 = Th + 2;
    dim3 g5(Bn, (Mn + 63) / 64, (To5 + 15) / 16), g3(Bn, (Mn + 63) / 64, (Th + 15) / 16);
    const unsigned short *W1[4], *W2[4];
    const float *Bb1[4], *Bb2[4];
    for (int j = 0; j < 4; ++j) {
      W1[j] = w1r + (size_t)(ni * 4 + j) * 321 * 1605;
      Bb1[j] = tb1 + (size_t)(ni * 4 + j) * Mn;
      W2[j] = w2r + (size_t)(ni * 4 + j) * 321 * 963;
      Bb2[j] = tb2 + (size_t)(ni * 4 + j) * Mn;
    }
    conv_branch<5, 0><<<g5, 128, 0, stream>>>(E, Th, W1[0], Bb1[0], nullptr, T1, To5);
    conv_branch<5, 0><<<g5, 128, 0, stream>>>(O, Th, W1[1], Bb1[1], nullptr, T2, To5);
    conv_branch<3, 1><<<g3, 128, 0, stream>>>(T2, To5, W2[1], Bb2[1], E, E, Th);  // c = e*exp(branch(o))
    conv_branch<3, 1><<<g3, 128, 0, stream>>>(T1, To5, W2[0], Bb2[0], O, O, Th);  // d = o*exp(branch(e))
    conv_branch<5, 0><<<g5, 128, 0, stream>>>(O, Th, W1[2], Bb1[2], nullptr, T1, To5);
    conv_branch<5, 0><<<g5, 128, 0, stream>>>(E, Th, W1[3], Bb1[3], nullptr, T2, To5);
    conv_branch<3, 2><<<g3, 128, 0, stream>>>(T1, To5, W2[2], Bb2[2], E, E, Th);  // eu = c + branch(d)
    conv_branch<3, 3><<<g3, 128, 0, stream>>>(T2, To5, W2[3], Bb2[3], O, O, Th);  // ou = d - branch(c)
  };
  auto zip = [&](const float* e, const float* o, float* dst, int Th) {
    int n = Bn * Mn * Th;
    zip_k<<<dim3((n + 255) / 256), 256, 0, stream>>>(e, o, (float2*)dst, n);
  };

  transpose_k<<<dim3(Bn, (Mn + 31) / 32, (Pn + 31) / 32), 256, 0, stream>>>(x, xT);

  node(0, xT, R0, R1, R2, R3, 96);                                       // eu0=R0, ou0=R1
  node(1, R0, R2, R2 + SZ48, R3, R3 + SZ50, 48);                         // eu1/ou1 in R2
  node(2, R2, R0, R0 + SZ24, R0 + 2 * SZ24, R0 + 2 * SZ24 + SZ26, 24);   // leaf on eu1
  zip(R0, R0 + SZ24, R2, 24);                                            // L2 -> R2[0:SZ48]
  node(3, R2 + SZ48, R0, R0 + SZ24, R0 + 2 * SZ24, R0 + 2 * SZ24 + SZ26, 24);
  zip(R0, R0 + SZ24, R2 + SZ48, 24);                                     // L3 -> R2[SZ48:]
  zip(R2, R2 + SZ48, R0, 48);                                            // RL -> R0
  node(4, R1, R2, R2 + SZ48, R3, R3 + SZ50, 48);                         // eu4/ou4 in R2
  node(5, R2, R1, R1 + SZ24, R1 + 2 * SZ24, R1 + 2 * SZ24 + SZ26, 24);
  zip(R1, R1 + SZ24, R2, 24);                                            // L5 -> R2[0:SZ48]
  node(6, R2 + SZ48, R1, R1 + SZ24, R1 + 2 * SZ24, R1 + 2 * SZ24 + SZ26, 24);
  zip(R1, R1 + SZ24, R2 + SZ48, 24);                                     // L6 -> R2[SZ48:]
  zip(R2, R2 + SZ48, R1, 48);                                            // RR -> R1
  {
    int n = Bn * Mn * 96;
    zipaddx_k<<<dim3((n + 255) / 256), 256, 0, stream>>>(R0, R1, (const float2*)xT, (float2*)XR, n);
  }

  conv2d_k<<<dim3(Bn, 2, (Ln + 15) / 16), 256, 0, stream>>>(XR, c1wr, c1b, Cc);
  gemm_gi<<<dim3((Ln * Bn) / 64, 384 / 64), 256, 0, stream>>>(Cc, g1wih, g1bih, R5);
  gru1_k<<<dim3(Bn / 2), 384, 0, stream>>>(R5, g1whh, g1bhh, h1);
  gis_k<<<dim3(PTn, Bn), 256, 0, stream>>>(Cc, gswih, gsbih, gis);
  grus_k<<<dim3((Bn * SKIPn) / 256), 256, 0, stream>>>(gis, gswhh, gsbhh, hsb);
  final_k<<<dim3(Bn), 384, 0, stream>>>(h1, hsb, l1w, l1b, XR, hww, hwb, out);
}

// Round 3
// 4304.557 us; speedup vs baseline: 5.3944x; 4.1877x over previous
//
#include <hip/hip_runtime.h>
#include <cstddef>
#include <cstdint>

#define Bn 256
#define Pn 192
#define Mn 321
#define Mp 336     // padded channel dim (multiple of 16)
#define HIDCn 128
#define HIDRn 128
#define HIDSn 8
#define CKn 6
#define SKIPn 24
#define HWn 24
#define Ln 187   // Pn - CKn + 1
#define PTn 7

typedef _Float16 f16;
typedef f16 f16x8 __attribute__((ext_vector_type(8)));
typedef float f32x16 __attribute__((ext_vector_type(16)));

__device__ __forceinline__ float sigmf(float x) { return 1.f / (1.f + expf(-x)); }
__device__ __forceinline__ unsigned short f2bf(float v) { return (unsigned short)(__float_as_uint(v) >> 16); }
__device__ __forceinline__ float bf2f(unsigned short u) { return __uint_as_float(((unsigned)u) << 16); }

// ================= tree weight repack + fp16 cast =================
// in: tree_w (NB,4,M,M,K)  ->  out slabs: [slot][k][cib21][co384][ci16] f16
// slot = n*4 + jj, blk = c0 + c1*n + c2*(n>>1)
__global__ __launch_bounds__(256) void repack_w(const float* __restrict__ w, f16* __restrict__ out,
                                                int K, int c0, int c1, int c2) {
  int s = blockIdx.z;
  int n = s >> 2, jj = s & 3;
  int blk = c0 + c1 * n + c2 * (n >> 1);
  int kcib = blockIdx.y;
  int k = kcib / 21, cib = kcib - 21 * k;
  int idx = blockIdx.x * 256 + threadIdx.x;  // [0, 6144)
  int co = idx >> 4, cc = idx & 15;
  int ci = cib * 16 + cc;
  f16 val = (f16)0.f;
  if (co < Mn && ci < Mn)
    val = (f16)w[(((size_t)(blk * 4 + jj) * Mn + co) * Mn + ci) * K + k];
  out[(((size_t)s * K + k) * 21 + cib) * 6144 + idx] = val;
}

// ================= conv2d weight repack (fp32) =================
__global__ __launch_bounds__(256) void repack_t(const float* __restrict__ in, float* __restrict__ out,
                                                int rows, int cols) {
  __shared__ float t[32][33];
  int r0 = blockIdx.x * 32, c0 = blockIdx.y * 32;
  int tx = threadIdx.x & 31, ty = threadIdx.x >> 5;
  for (int i = ty; i < 32; i += 8) {
    int r = r0 + i, c = c0 + tx;
    t[i][tx] = (r < rows && c < cols) ? in[(size_t)r * cols + c] : 0.f;
  }
  __syncthreads();
  for (int i = ty; i < 32; i += 8) {
    int c = c0 + i, r = r0 + tx;
    if (c < cols && r < rows) out[(size_t)c * rows + r] = t[tx][i];
  }
}

// ================= deinterleave -> e/o hi/lo planes =================
// out[z][B][Th][Mp], z = c*2 + eo; parent rows = 2*Th
__global__ __launch_bounds__(256) void deint_mk(const float* __restrict__ x32,
                                                const f16* __restrict__ ph, const f16* __restrict__ pl,
                                                int Thp, f16* __restrict__ oh, f16* __restrict__ ol, int Th) {
  int b = blockIdx.x, t = blockIdx.y, z = blockIdx.z;
  int c = z >> 1, eo = z & 1;
  int srow = 2 * t + eo;
  size_t ooff = (((size_t)z * Bn + b) * Th + t) * Mp;
  if (x32) {
    const float* xp = x32 + ((size_t)b * Pn + srow) * Mn;
    for (int m = threadIdx.x; m < Mp; m += 256) {
      float v = (m < Mn) ? xp[m] : 0.f;
      f16 hi = (f16)v;
      oh[ooff + m] = hi;
      ol[ooff + m] = (f16)(v - (float)hi);
    }
  } else {
    const uint32_t* ih = (const uint32_t*)(ph + (((size_t)c * Bn + b) * Thp + srow) * Mp);
    const uint32_t* il = (const uint32_t*)(pl + (((size_t)c * Bn + b) * Thp + srow) * Mp);
    uint32_t* uh = (uint32_t*)(oh + ooff);
    uint32_t* ul = (uint32_t*)(ol + ooff);
    for (int i = threadIdx.x; i < Mp / 2; i += 256) { uh[i] = ih[i]; ul[i] = il[i]; }
  }
}

// ================= MFMA branch conv =================
// C[(b,t)][co] = sum_{ci,k} X[t+k-PADL(clamped)][ci] * W_k[co][ci]
// 2-pass fp16: acc += W*x_hi; acc += W*x_lo.  Block: 256thr/4 waves; tile m64(4b x 16t) x co384.
// MK 0: leaky   MK 1: out = src*exp(tanh(v))   MK 2: out = src +/- tanh(v) (by z&1)
template <int K, int MK>
__global__ __launch_bounds__(256) void conv_mfma(
    const f16* __restrict__ inh, const f16* __restrict__ inl, long in_zs, int Tin,
    const f16* __restrict__ Wb, int wc0, int wc1, int wc2, int wjoff,
    const float* __restrict__ biasb,
    const f16* __restrict__ srch, const f16* __restrict__ srcl, long src_zs,
    f16* __restrict__ outh, f16* __restrict__ outl, long out_zs, int Tout) {
  constexpr int PADL = (K == 5) ? 3 : 0;
  constexpr int SLAB = K * 21 * 6144;  // halves per slot
  __shared__ f16 sX[2][64][16];
  __shared__ f16 sW[384][16];
  int z = blockIdx.z;
  int n = z >> 1, j = z & 1;
  int blk = wc0 + wc1 * n + wc2 * (n >> 1);
  int slot = n * 4 + wjoff + j;
  const uint32_t* inu0 = (const uint32_t*)(inh + (size_t)z * in_zs);
  const uint32_t* inu1 = (const uint32_t*)(inl + (size_t)z * in_zs);
  const uint32_t* wsl = (const uint32_t*)(Wb + (size_t)slot * SLAB);
  const float* bias = biasb + (size_t)(blk * 4 + wjoff + j) * Mn;
  int b0 = blockIdx.x * 4;
  int t0 = blockIdx.y * 16;
  int tid = threadIdx.x;
  int lane = tid & 63;
  int wv = tid >> 6;
  int wm = wv & 1, wc = wv >> 1;

  f32x16 acc[6];
#pragma unroll
  for (int i = 0; i < 6; ++i)
#pragma unroll
    for (int q = 0; q < 16; ++q) acc[i][q] = 0.f;

  uint32_t* sXu = (uint32_t*)&sX[0][0][0];
  uint32_t* sWu = (uint32_t*)&sW[0][0];

#pragma unroll 1
  for (int k = 0; k < K; ++k) {
#pragma unroll 1
    for (int cib = 0; cib < 21; ++cib) {
      // stage X: 1024 uints (2 planes x 64 rows x 8)
#pragma unroll
      for (int jj = 0; jj < 4; ++jj) {
        int i = tid + jj * 256;
        int pl = i >> 9;
        int m = (i >> 3) & 63;
        int u = i & 7;
        int bl = m >> 4, tt = m & 15;
        int ts = t0 + tt + k - PADL;
        ts = max(0, min(ts, Tin - 1));
        size_t go = (((size_t)(b0 + bl) * Tin + ts) * Mp + cib * 16) >> 1;
        sXu[i] = (pl ? inu1 : inu0)[go + u];
      }
      // stage W: 3072 uints, contiguous slab
      const uint32_t* wp = wsl + ((size_t)k * 21 + cib) * 3072;
#pragma unroll
      for (int jj = 0; jj < 12; ++jj) sWu[tid + jj * 256] = wp[tid + jj * 256];
      __syncthreads();
      int mo = wm * 32 + (lane & 31);
      int cio = (lane >> 5) * 8;
      f16x8 ah = *(const f16x8*)&sX[0][mo][cio];
      f16x8 al = *(const f16x8*)&sX[1][mo][cio];
#pragma unroll
      for (int ct = 0; ct < 6; ++ct) {
        f16x8 bw = *(const f16x8*)&sW[wc * 192 + ct * 32 + (lane & 31)][cio];
        acc[ct] = __builtin_amdgcn_mfma_f32_32x32x16_f16(ah, bw, acc[ct], 0, 0, 0);
        acc[ct] = __builtin_amdgcn_mfma_f32_32x32x16_f16(al, bw, acc[ct], 0, 0, 0);
      }
      __syncthreads();
    }
  }
  // epilogue
  f16* o_h = outh + (size_t)z * out_zs;
  f16* o_l = outl + (size_t)z * out_zs;
  const f16* s_h = srch ? srch + (size_t)(z ^ 1) * src_zs : nullptr;
  const f16* s_l = srcl ? srcl + (size_t)(z ^ 1) * src_zs : nullptr;
#pragma unroll
  for (int ct = 0; ct < 6; ++ct) {
    int co = wc * 192 + ct * 32 + (lane & 31);
    if (co >= Mp) continue;
    float bb = (co < Mn) ? bias[co] : 0.f;
#pragma unroll
    for (int r = 0; r < 16; ++r) {
      int row = (r & 3) + 8 * (r >> 2) + 4 * (lane >> 5);
      int m = wm * 32 + row;
      int bl = m >> 4, tt = m & 15;
      int t = t0 + tt;
      if (t >= Tout) continue;
      size_t oo = (((size_t)(b0 + bl)) * Tout + t) * Mp + co;
      float res;
      if (co >= Mn) {
        res = 0.f;
      } else {
        float v = acc[ct][r] + bb;
        if constexpr (MK == 0) {
          res = v > 0.f ? v : 0.01f * v;
        } else {
          float s = (float)s_h[oo] + (float)s_l[oo];
          float th = tanhf(v);
          if constexpr (MK == 1) res = s * expf(th);
          else res = (j == 0) ? s + th : s - th;
        }
      }
      f16 hi = (f16)res;
      o_h[oo] = hi;
      o_l[oo] = (f16)(res - (float)hi);
    }
  }
}

// ================= final combine: XR = x + interleave(leaves) =================
__global__ __launch_bounds__(256) void combine_k(const float* __restrict__ x, const f16* __restrict__ lh,
                                                 const f16* __restrict__ ll, float* __restrict__ XR) {
  int b = blockIdx.x, p = blockIdx.y;
  int c = ((p & 1) << 2) | (p & 2) | ((p >> 2) & 1);
  int row = p >> 3;
  size_t li = (((size_t)c * Bn + b) * 24 + row) * Mp;
  size_t xi = ((size_t)b * Pn + p) * Mn;
  for (int m = threadIdx.x; m < Mn; m += 256)
    XR[xi + m] = x[xi + m] + (float)lh[li + m] + (float)ll[li + m];
}

// ================= conv2d: XR (B,P,Mn) -> Cc (L,B,HIDC), relu =================
__global__ __launch_bounds__(256) void conv2d_k(const float* __restrict__ xr, const float* __restrict__ wT,
                                                const float* __restrict__ bias, float* __restrict__ out) {
  constexpr int LT = 16;
  constexpr int TW = LT + CKn - 1;  // 21
  __shared__ float sx[Mn * TW];
  int nb = blockIdx.x;
  int i0 = blockIdx.y * 64;
  int l0 = blockIdx.z * LT;
  int tid = threadIdx.x;
  for (int idx = tid; idx < TW * Mn; idx += 256) {
    int pl = idx / Mn, m = idx - pl * Mn;
    int p = min(l0 + pl, Pn - 1);
    sx[m * TW + pl] = xr[((size_t)nb * Pn + p) * Mn + m];
  }
  __syncthreads();
  int i = i0 + (tid & 63);
  int lb = (tid >> 6) * 4;
  float acc[4] = {0.f, 0.f, 0.f, 0.f};
  for (int m = 0; m < Mn; ++m) {
    float xv[4 + CKn - 1];
#pragma unroll
    for (int jj = 0; jj < 9; ++jj) xv[jj] = sx[m * TW + lb + jj];
#pragma unroll
    for (int k = 0; k < CKn; ++k) {
      float wv = wT[(size_t)(k * Mn + m) * HIDCn + i];
#pragma unroll
      for (int tt = 0; tt < 4; ++tt) acc[tt] = fmaf(wv, xv[tt + k], acc[tt]);
    }
  }
  float bb = bias[i];
#pragma unroll
  for (int tt = 0; tt < 4; ++tt) {
    int l = l0 + lb + tt;
    if (l < Ln) {
      float y = acc[tt] + bb;
      out[((size_t)l * Bn + nb) * HIDCn + i] = y > 0.f ? y : 0.f;
    }
  }
}

// ================= GRU1 input GEMM =================
__global__ __launch_bounds__(256) void gemm_gi(const float* __restrict__ A, const float* __restrict__ W,
                                               const float* __restrict__ bias, float* __restrict__ out) {
  __shared__ float sA[64][129];
  __shared__ float sB[64][129];
  int r0 = blockIdx.x * 64, c0 = blockIdx.y * 64;
  int tid = threadIdx.x;
  for (int idx = tid; idx < 64 * 128; idx += 256) {
    int r = idx >> 7, k = idx & 127;
    sA[r][k] = A[(size_t)(r0 + r) * 128 + k];
    sB[r][k] = W[(size_t)(c0 + r) * 128 + k];
  }
  __syncthreads();
  int tx = tid & 15, ty = tid >> 4;
  int rr = ty * 4, cc = tx * 4;
  float acc[4][4] = {};
  for (int k = 0; k < 128; ++k) {
    float a[4], bv[4];
#pragma unroll
    for (int u = 0; u < 4; ++u) a[u] = sA[rr + u][k];
#pragma unroll
    for (int v = 0; v < 4; ++v) bv[v] = sB[cc + v][k];
#pragma unroll
    for (int u = 0; u < 4; ++u)
#pragma unroll
      for (int v = 0; v < 4; ++v) acc[u][v] = fmaf(a[u], bv[v], acc[u][v]);
  }
#pragma unroll
  for (int u = 0; u < 4; ++u)
#pragma unroll
    for (int v = 0; v < 4; ++v)
      out[(size_t)(r0 + rr + u) * 384 + (c0 + cc + v)] = acc[u][v] + bias[c0 + cc + v];
}

// ================= GRU1 recurrent =================
__global__ __launch_bounds__(384) void gru1_k(const float* __restrict__ gi, const float* __restrict__ whh,
                                              const float* __restrict__ bhh, float* __restrict__ hout) {
  __shared__ unsigned short swhh[384 * 130];
  __shared__ float hs[2][128];
  __shared__ float ghb[384][2];
  int n0 = blockIdx.x * 2;
  int tid = threadIdx.x;
  for (int idx = tid; idx < 384 * 128; idx += 384) {
    int r = idx >> 7, i2 = idx & 127;
    swhh[r * 130 + i2] = f2bf(whh[idx]);
  }
  if (tid < 256) hs[tid >> 7][tid & 127] = 0.f;
  float bias_g = bhh[tid];
  __syncthreads();
  int r = tid >> 7, j = tid & 127;
  for (int t = 0; t < Ln; ++t) {
    float g0 = bias_g, g1 = bias_g;
    const unsigned short* wr = swhh + tid * 130;
    for (int i = 0; i < 128; ++i) {
      float wv = bf2f(wr[i]);
      g0 = fmaf(wv, hs[0][i], g0);
      g1 = fmaf(wv, hs[1][i], g1);
    }
    ghb[tid][0] = g0;
    ghb[tid][1] = g1;
    __syncthreads();
    float hnew = 0.f;
    if (tid < 256) {
      const float* girow = gi + ((size_t)t * Bn + (n0 + r)) * 384;
      float gir = girow[j], giz = girow[128 + j], gin = girow[256 + j];
      float hr = ghb[j][r], hz = ghb[128 + j][r], hn = ghb[256 + j][r];
      float rg = sigmf(gir + hr);
      float zg = sigmf(giz + hz);
      float ng = tanhf(gin + rg * hn);
      hnew = (1.f - zg) * ng + zg * hs[r][j];
    }
    if (tid < 256) hs[r][j] = hnew;
    __syncthreads();
  }
  if (tid < 256) hout[(size_t)(n0 + r) * 128 + j] = hs[r][j];
}

// ================= skip-GRU input gemm =================
__global__ __launch_bounds__(256) void gis_k(const float* __restrict__ cc, const float* __restrict__ wih,
                                             const float* __restrict__ bih, float* __restrict__ gi) {
  __shared__ float sx[24 * 128];
  int t = blockIdx.x, b = blockIdx.y;
  int tid = threadIdx.x;
  for (int idx = tid; idx < 24 * 128; idx += 256) {
    int sk = idx >> 7, i = idx & 127;
    int l = 19 + t * 24 + sk;
    sx[idx] = cc[((size_t)l * Bn + b) * HIDCn + i];
  }
  __syncthreads();
  for (int idx = tid; idx < 576; idx += 256) {
    int sk = idx / 24, g = idx - sk * 24;
    float a = bih[g];
    for (int i = 0; i < 128; ++i) a = fmaf(sx[sk * 128 + i], wih[g * 128 + i], a);
    gi[((size_t)t * (Bn * SKIPn) + b * 24 + sk) * 24 + g] = a;
  }
}

// ================= skip-GRU recurrent =================
__global__ __launch_bounds__(256) void grus_k(const float* __restrict__ gi, const float* __restrict__ whh,
                                              const float* __restrict__ bhh, float* __restrict__ hout) {
  __shared__ float sw[24 * 8];
  __shared__ float sb[24];
  int tid = threadIdx.x;
  int n = blockIdx.x * 256 + tid;
  if (tid < 192) sw[tid] = whh[tid];
  if (tid < 24) sb[tid] = bhh[tid];
  __syncthreads();
  float h[8];
#pragma unroll
  for (int jj = 0; jj < 8; ++jj) h[jj] = 0.f;
  for (int t = 0; t < PTn; ++t) {
    const float* gir = gi + ((size_t)t * (Bn * SKIPn) + n) * 24;
    float gh[24];
#pragma unroll
    for (int g = 0; g < 24; ++g) {
      float a = sb[g];
#pragma unroll
      for (int jj = 0; jj < 8; ++jj) a = fmaf(sw[g * 8 + jj], h[jj], a);
      gh[g] = a;
    }
#pragma unroll
    for (int jj = 0; jj < 8; ++jj) {
      float rg = sigmf(gir[jj] + gh[jj]);
      float zg = sigmf(gir[8 + jj] + gh[8 + jj]);
      float ng = tanhf(gir[16 + jj] + rg * gh[16 + jj]);
      h[jj] = (1.f - zg) * ng + zg * h[jj];
    }
  }
#pragma unroll
  for (int jj = 0; jj < 8; ++jj) hout[(size_t)n * 8 + jj] = h[jj];
}

// ================= final linear + highway =================
__global__ __launch_bounds__(384) void final_k(const float* __restrict__ h1, const float* __restrict__ hsb,
                                               const float* __restrict__ lw, const float* __restrict__ lb,
                                               const float* __restrict__ xr, const float* __restrict__ hww,
                                               const float* __restrict__ hwb, float* __restrict__ out) {
  __shared__ float sr[320];
  __shared__ float shw[24];
  int b = blockIdx.x;
  int tid = threadIdx.x;
  if (tid < 128) sr[tid] = h1[(size_t)b * 128 + tid];
  else if (tid < 320) sr[tid] = hsb[(size_t)b * 192 + (tid - 128)];
  if (tid >= 320 && tid < 344) shw[tid - 320] = hww[tid - 320];
  __syncthreads();
  int m = tid;
  if (m >= Mn) return;
  float a = lb[m];
  const float* wr = lw + (size_t)m * 320;
  for (int c = 0; c < 320; ++c) a = fmaf(sr[c], wr[c], a);
  float z = hwb[0];
  const float* xrr = xr + ((size_t)b * Pn + (Pn - HWn)) * Mn + m;
#pragma unroll
  for (int k = 0; k < HWn; ++k) z = fmaf(xrr[(size_t)k * Mn], shw[k], z);
  out[(size_t)b * Mn + m] = a + z;
}

extern "C" void kernel_launch(void* const* d_in, const int* in_sizes, int n_in,
                              void* d_out, int out_size, void* d_ws, size_t ws_size,
                              hipStream_t stream) {
  const float* x = (const float*)d_in[0];
  const float* tw1 = (const float*)d_in[1];
  const float* tb1 = (const float*)d_in[2];
  const float* tw2 = (const float*)d_in[3];
  const float* tb2 = (const float*)d_in[4];
  const float* c1w = (const float*)d_in[5];
  const float* c1b = (const float*)d_in[6];
  const float* g1wih = (const float*)d_in[7];
  const float* g1whh = (const float*)d_in[8];
  const float* g1bih = (const float*)d_in[9];
  const float* g1bhh = (const float*)d_in[10];
  const float* gswih = (const float*)d_in[11];
  const float* gswhh = (const float*)d_in[12];
  const float* gsbih = (const float*)d_in[13];
  const float* gsbhh = (const float*)d_in[14];
  const float* l1w = (const float*)d_in[15];
  const float* l1b = (const float*)d_in[16];
  const float* hww = (const float*)d_in[17];
  const float* hwb = (const float*)d_in[18];
  float* out = (float*)d_out;

  // ---------- workspace plan (~246 MB) ----------
  const size_t HA = 17891328ull, HB = 17891328ull, HC = 17203200ull;  // halves per plane
  f16* A_hi = (f16*)d_ws;
  f16* A_lo = A_hi + HA;
  f16* B_hi = A_lo + HA;
  f16* B_lo = B_hi + HB;
  f16* C_hi = B_lo + HB;
  f16* C_lo = C_hi + HC;
  f16* Wl1 = C_lo + HC;                    // 16*5*21*6144 = 10,321,920 halves
  f16* Wl2 = Wl1 + 10321920ull;            // 16*3*21*6144 = 6,193,152 halves
  float* c1wr = (float*)(Wl2 + 6193152ull);
  // post-tree aliases
  float* XR = (float*)B_hi;                // 63.1 MB in B region
  float* Cc = (float*)A_hi;                // 24.5 MB in A_hi
  float* giA = (float*)C_hi;               // 73.5 MB spanning C + (dead) Wl1
  float* h1 = (float*)((char*)d_ws + 24600000ull);
  float* hsb = h1 + 32768;
  float* gis = hsb + 49152;

  // region assignment per level: {EO, S1, CD, S3, EU}
  f16* EOh[3] = {A_hi, A_hi, B_hi};  f16* EOl[3] = {A_lo, A_lo, B_lo};
  f16* S1h[3] = {B_hi, C_hi, A_hi};  f16* S1l[3] = {B_lo, C_lo, A_lo};
  f16* CDh[3] = {C_hi, B_hi, C_hi};  f16* CDl[3] = {C_lo, B_lo, C_lo};
  f16* S3h[3] = {A_hi, A_hi, B_hi};  f16* S3l[3] = {A_lo, A_lo, B_lo};
  f16* EUh[3] = {B_hi, C_hi, A_hi};  f16* EUl[3] = {B_lo, C_lo, A_lo};
  const int WC0[3] = {0, 1, 2}, WC1[3] = {0, 3, 1}, WC2[3] = {0, 0, 1};

  // conv2d weight repack
  repack_t<<<dim3(4, 61), 256, 0, stream>>>(c1w, c1wr, 128, 1926);

  for (int L = 0; L < 3; ++L) {
    int NL = 1 << L;
    int Th = 96 >> L;
    long zsEO = (long)Bn * Th * Mp;
    long zsS1 = (long)Bn * (Th + 2) * Mp;
    // repack this level's weights
    repack_w<<<dim3(24, 5 * 21, NL * 4), 256, 0, stream>>>(tw1, Wl1, 5, WC0[L], WC1[L], WC2[L]);
    repack_w<<<dim3(24, 3 * 21, NL * 4), 256, 0, stream>>>(tw2, Wl2, 3, WC0[L], WC1[L], WC2[L]);
    // deinterleave
    if (L == 0)
      deint_mk<<<dim3(Bn, Th, 2), 256, 0, stream>>>(x, nullptr, nullptr, 0, EOh[0], EOl[0], Th);
    else
      deint_mk<<<dim3(Bn, Th, 2 * NL), 256, 0, stream>>>(nullptr, EUh[L - 1], EUl[L - 1], 2 * Th,
                                                         EOh[L], EOl[L], Th);
    int tt1 = (Th + 2 + 15) / 16, tt2 = (Th + 15) / 16;
    int Z = 2 * NL;
    // stage1: leaky(conv5(e|o))
    conv_mfma<5, 0><<<dim3(64, tt1, Z), 256, 0, stream>>>(
        EOh[L], EOl[L], zsEO, Th, Wl1, WC0[L], WC1[L], WC2[L], 0, tb1,
        nullptr, nullptr, 0, S1h[L], S1l[L], zsS1, Th + 2);
    // stage2: d = o*exp(tanh(conv3)), c = e*exp(tanh(conv3))
    conv_mfma<3, 1><<<dim3(64, tt2, Z), 256, 0, stream>>>(
        S1h[L], S1l[L], zsS1, Th + 2, Wl2, WC0[L], WC1[L], WC2[L], 0, tb2,
        EOh[L], EOl[L], zsEO, CDh[L], CDl[L], zsEO, Th);
    // stage3: leaky(conv5(d|c))
    conv_mfma<5, 0><<<dim3(64, tt1, Z), 256, 0, stream>>>(
        CDh[L], CDl[L], zsEO, Th, Wl1, WC0[L], WC1[L], WC2[L], 2, tb1,
        nullptr, nullptr, 0, S3h[L], S3l[L], zsS1, Th + 2);
    // stage4: eu = c + tanh(conv3), ou = d - tanh(conv3)
    conv_mfma<3, 2><<<dim3(64, tt2, Z), 256, 0, stream>>>(
        S3h[L], S3l[L], zsS1, Th + 2, Wl2, WC0[L], WC1[L], WC2[L], 2, tb2,
        CDh[L], CDl[L], zsEO, EUh[L], EUl[L], zsEO, Th);
  }

  // XR = x + res1 (row-gather of leaves)
  combine_k<<<dim3(Bn, Pn), 256, 0, stream>>>(x, EUh[2], EUl[2], XR);

  conv2d_k<<<dim3(Bn, 2, (Ln + 15) / 16), 256, 0, stream>>>(XR, c1wr, c1b, Cc);
  gemm_gi<<<dim3((Ln * Bn) / 64, 384 / 64), 256, 0, stream>>>(Cc, g1wih, g1bih, giA);
  gru1_k<<<dim3(Bn / 2), 384, 0, stream>>>(giA, g1whh, g1bhh, h1);
  gis_k<<<dim3(PTn, Bn), 256, 0, stream>>>(Cc, gswih, gsbih, gis);
  grus_k<<<dim3((Bn * SKIPn) / 256), 256, 0, stream>>>(gis, gswhh, gsbhh, hsb);
  final_k<<<dim3(Bn), 384, 0, stream>>>(h1, hsb, l1w, l1b, XR, hww, hwb, out);
}

// Round 4
// 3468.979 us; speedup vs baseline: 6.6938x; 1.2409x over previous
//
#include <hip/hip_runtime.h>
#include <cstddef>
#include <cstdint>

#define Bn 256
#define Pn 192
#define Mn 321
#define Mp 336     // padded channel dim (multiple of 16)
#define HIDCn 128
#define HIDRn 128
#define HIDSn 8
#define CKn 6
#define SKIPn 24
#define HWn 24
#define Ln 187   // Pn - CKn + 1
#define PTn 7

typedef _Float16 f16;
typedef f16 f16x2 __attribute__((ext_vector_type(2)));
typedef f16 f16x8 __attribute__((ext_vector_type(8)));
typedef float f32x16 __attribute__((ext_vector_type(16)));

__device__ __forceinline__ float sigmf(float x) { return 1.f / (1.f + expf(-x)); }

// ================= tree weight repack + fp16 cast =================
// in: tree_w (NB,4,M,M,K) -> slabs: [slot][k][cib21][co384][ci16] f16
__global__ __launch_bounds__(256) void repack_w(const float* __restrict__ w, f16* __restrict__ out,
                                                int K, int c0, int c1, int c2) {
  int s = blockIdx.z;
  int n = s >> 2, jj = s & 3;
  int blk = c0 + c1 * n + c2 * (n >> 1);
  int kcib = blockIdx.y;
  int k = kcib / 21, cib = kcib - 21 * k;
  int idx = blockIdx.x * 256 + threadIdx.x;  // [0, 6144)
  int co = idx >> 4, cc = idx & 15;
  int ci = cib * 16 + cc;
  f16 val = (f16)0.f;
  if (co < Mn && ci < Mn)
    val = (f16)w[(((size_t)(blk * 4 + jj) * Mn + co) * Mn + ci) * K + k];
  out[(((size_t)s * K + k) * 21 + cib) * 6144 + idx] = val;
}

// ================= conv2d weight repack (fp32) =================
__global__ __launch_bounds__(256) void repack_t(const float* __restrict__ in, float* __restrict__ out,
                                                int rows, int cols) {
  __shared__ float t[32][33];
  int r0 = blockIdx.x * 32, c0 = blockIdx.y * 32;
  int tx = threadIdx.x & 31, ty = threadIdx.x >> 5;
  for (int i = ty; i < 32; i += 8) {
    int r = r0 + i, c = c0 + tx;
    t[i][tx] = (r < rows && c < cols) ? in[(size_t)r * cols + c] : 0.f;
  }
  __syncthreads();
  for (int i = ty; i < 32; i += 8) {
    int c = c0 + i, r = r0 + tx;
    if (c < cols && r < rows) out[(size_t)c * rows + r] = t[tx][i];
  }
}

// ================= deinterleave -> e/o planes (single fp16) =================
__global__ __launch_bounds__(256) void deint_k(const float* __restrict__ x32,
                                               const f16* __restrict__ parent, int Thp,
                                               f16* __restrict__ o, int Th) {
  int b = blockIdx.x, t = blockIdx.y, z = blockIdx.z;
  int c = z >> 1, eo = z & 1;
  int srow = 2 * t + eo;
  size_t ooff = (((size_t)z * Bn + b) * Th + t) * Mp;
  if (x32) {
    const float* xp = x32 + ((size_t)b * Pn + srow) * Mn;
    for (int m = threadIdx.x; m < Mp; m += 256)
      o[ooff + m] = (m < Mn) ? (f16)xp[m] : (f16)0.f;
  } else {
    const uint32_t* ip = (const uint32_t*)(parent + (((size_t)c * Bn + b) * Thp + srow) * Mp);
    uint32_t* op = (uint32_t*)(o + ooff);
    for (int i = threadIdx.x; i < Mp / 2; i += 256) op[i] = ip[i];
  }
}

// ================= MFMA branch conv (single-pass fp16) =================
// m-tile 128 = 4 batch x 32 t; co 384 over 2 wave-halves; 512 thr / 8 waves.
// MK 0: leaky   MK 1: out = src*exp(tanh(v))   MK 2: out = src +/- tanh(v) (by z&1)
template <int K, int MK>
__global__ __launch_bounds__(512, 2) void conv_mfma(
    const f16* __restrict__ inz, long in_zs, int Tin,
    const f16* __restrict__ Wb, int wc0, int wc1, int wc2, int wjoff,
    const float* __restrict__ biasb,
    const f16* __restrict__ srcz, long src_zs,
    f16* __restrict__ outz, long out_zs, int Tout) {
  constexpr int PADL = (K == 5) ? 3 : 0;
  constexpr int TWIN = 32 + K - 1;
  constexpr int SLAB = K * 21 * 6144;
  __shared__ __align__(16) f16 sX[4][40][24];   // [batch][t-window][ci pad to 48B]
  __shared__ __align__(16) f16 sW[384][24];
  int z = blockIdx.z;
  int nnode = z >> 1, j = z & 1;
  int blk = wc0 + wc1 * nnode + wc2 * (nnode >> 1);
  int slot = nnode * 4 + wjoff + j;
  const uint32_t* inu = (const uint32_t*)(inz + (size_t)z * in_zs);
  const uint32_t* wsl = (const uint32_t*)(Wb + (size_t)slot * SLAB);
  const float* bias = biasb + (size_t)(blk * 4 + wjoff + j) * Mn;
  int b0 = blockIdx.x * 4;
  int t0 = blockIdx.y * 32;
  int tid = threadIdx.x;
  int lane = tid & 63;
  int wv = tid >> 6;
  int wm = wv & 3, wc = wv >> 2;

  f32x16 acc[6];
#pragma unroll
  for (int i = 0; i < 6; ++i)
#pragma unroll
    for (int q = 0; q < 16; ++q) acc[i][q] = 0.f;

  uint32_t* sXu = (uint32_t*)&sX[0][0][0];
  uint32_t* sWu = (uint32_t*)&sW[0][0];

#pragma unroll 1
  for (int cib = 0; cib < 21; ++cib) {
    // stage X window once per cib (k-shift applied at read time)
    constexpr int NX = 4 * TWIN * 8;
    for (int idx = tid; idx < NX; idx += 512) {
      int u = idx & 7;
      int rr = idx >> 3;
      int tt = rr % TWIN;
      int bl = rr / TWIN;
      int ts = t0 + tt - PADL;
      ts = max(0, min(ts, Tin - 1));
      sXu[(bl * 40 + tt) * 12 + u] =
          inu[((((size_t)(b0 + bl)) * Tin + ts) * Mp + cib * 16) / 2 + u];
    }
#pragma unroll 1
    for (int k = 0; k < K; ++k) {
      const uint32_t* wp = wsl + ((size_t)(k * 21 + cib)) * 3072;
#pragma unroll
      for (int jj = 0; jj < 6; ++jj) {
        int idx = tid + jj * 512;
        int co = idx >> 3, u2 = idx & 7;
        sWu[co * 12 + u2] = wp[idx];
      }
      __syncthreads();
      f16x8 ah = *(const f16x8*)&sX[wm][(lane & 31) + k][(lane >> 5) * 8];
#pragma unroll
      for (int ct = 0; ct < 6; ++ct) {
        f16x8 bw = *(const f16x8*)&sW[wc * 192 + ct * 32 + (lane & 31)][(lane >> 5) * 8];
        acc[ct] = __builtin_amdgcn_mfma_f32_32x32x16_f16(ah, bw, acc[ct], 0, 0, 0);
      }
      __syncthreads();
    }
  }
  // epilogue
  f16* o = outz + (size_t)z * out_zs;
  const f16* s = srcz ? srcz + (size_t)(z ^ 1) * src_zs : nullptr;
#pragma unroll
  for (int ct = 0; ct < 6; ++ct) {
    int co = wc * 192 + ct * 32 + (lane & 31);
    if (co >= Mp) continue;
    float bb = (co < Mn) ? bias[co] : 0.f;
#pragma unroll
    for (int r = 0; r < 16; ++r) {
      int row = (r & 3) + 8 * (r >> 2) + 4 * (lane >> 5);
      int t = t0 + row;
      if (t >= Tout) continue;
      size_t oo = (((size_t)(b0 + wm)) * Tout + t) * Mp + co;
      float res;
      if (co >= Mn) {
        res = 0.f;
      } else {
        float v = acc[ct][r] + bb;
        if constexpr (MK == 0) {
          res = v > 0.f ? v : 0.01f * v;
        } else {
          float sv = (float)s[oo];
          float th = tanhf(v);
          if constexpr (MK == 1) res = sv * expf(th);
          else res = (j == 0) ? sv + th : sv - th;
        }
      }
      o[oo] = (f16)res;
    }
  }
}

// ================= final combine: XR = x + interleave(leaves) =================
__global__ __launch_bounds__(256) void combine_k(const float* __restrict__ x, const f16* __restrict__ lv,
                                                 float* __restrict__ XR) {
  int b = blockIdx.x, p = blockIdx.y;
  int c = ((p & 1) << 2) | (p & 2) | ((p >> 2) & 1);
  int row = p >> 3;
  size_t li = (((size_t)c * Bn + b) * 24 + row) * Mp;
  size_t xi = ((size_t)b * Pn + p) * Mn;
  for (int m = threadIdx.x; m < Mn; m += 256)
    XR[xi + m] = x[xi + m] + (float)lv[li + m];
}

// ================= conv2d: XR (B,P,Mn) -> Cc (L,B,HIDC), relu =================
__global__ __launch_bounds__(256) void conv2d_k(const float* __restrict__ xr, const float* __restrict__ wT,
                                                const float* __restrict__ bias, float* __restrict__ out) {
  constexpr int LT = 16;
  constexpr int TW = LT + CKn - 1;  // 21
  __shared__ float sx[Mn * TW];
  int nb = blockIdx.x;
  int i0 = blockIdx.y * 64;
  int l0 = blockIdx.z * LT;
  int tid = threadIdx.x;
  for (int idx = tid; idx < TW * Mn; idx += 256) {
    int pl = idx / Mn, m = idx - pl * Mn;
    int p = min(l0 + pl, Pn - 1);
    sx[m * TW + pl] = xr[((size_t)nb * Pn + p) * Mn + m];
  }
  __syncthreads();
  int i = i0 + (tid & 63);
  int lb = (tid >> 6) * 4;
  float acc[4] = {0.f, 0.f, 0.f, 0.f};
  for (int m = 0; m < Mn; ++m) {
    float xv[4 + CKn - 1];
#pragma unroll
    for (int jj = 0; jj < 9; ++jj) xv[jj] = sx[m * TW + lb + jj];
#pragma unroll
    for (int k = 0; k < CKn; ++k) {
      float wv = wT[(size_t)(k * Mn + m) * HIDCn + i];
#pragma unroll
      for (int tt = 0; tt < 4; ++tt) acc[tt] = fmaf(wv, xv[tt + k], acc[tt]);
    }
  }
  float bb = bias[i];
#pragma unroll
  for (int tt = 0; tt < 4; ++tt) {
    int l = l0 + lb + tt;
    if (l < Ln) {
      float y = acc[tt] + bb;
      out[((size_t)l * Bn + nb) * HIDCn + i] = y > 0.f ? y : 0.f;
    }
  }
}

// ================= GRU1 input GEMM =================
__global__ __launch_bounds__(256) void gemm_gi(const float* __restrict__ A, const float* __restrict__ W,
                                               const float* __restrict__ bias, float* __restrict__ out) {
  __shared__ float sA[64][129];
  __shared__ float sB[64][129];
  int r0 = blockIdx.x * 64, c0 = blockIdx.y * 64;
  int tid = threadIdx.x;
  for (int idx = tid; idx < 64 * 128; idx += 256) {
    int r = idx >> 7, k = idx & 127;
    sA[r][k] = A[(size_t)(r0 + r) * 128 + k];
    sB[r][k] = W[(size_t)(c0 + r) * 128 + k];
  }
  __syncthreads();
  int tx = tid & 15, ty = tid >> 4;
  int rr = ty * 4, cc = tx * 4;
  float acc[4][4] = {};
  for (int k = 0; k < 128; ++k) {
    float a[4], bv[4];
#pragma unroll
    for (int u = 0; u < 4; ++u) a[u] = sA[rr + u][k];
#pragma unroll
    for (int v = 0; v < 4; ++v) bv[v] = sB[cc + v][k];
#pragma unroll
    for (int u = 0; u < 4; ++u)
#pragma unroll
      for (int v = 0; v < 4; ++v) acc[u][v] = fmaf(a[u], bv[v], acc[u][v]);
  }
#pragma unroll
  for (int u = 0; u < 4; ++u)
#pragma unroll
    for (int v = 0; v < 4; ++v)
      out[(size_t)(r0 + rr + u) * 384 + (c0 + cc + v)] = acc[u][v] + bias[c0 + cc + v];
}

// ================= GRU1 recurrent v2: 1 batch/block, whh in registers =================
__global__ __launch_bounds__(384) void gru1_k(const float* __restrict__ gi, const float* __restrict__ whh,
                                              const float* __restrict__ bhh, float* __restrict__ hout) {
  __shared__ __align__(16) uint32_t swc[64][68];  // chunk bounce: 64 rows x 64 f16-pairs
  __shared__ float hf[128];
  __shared__ __align__(16) uint32_t hp[64];       // h packed f16x2
  __shared__ float ghb[384];
  int n = blockIdx.x;
  int tid = threadIdx.x;
  int myc = tid >> 6, lr = tid & 63;
  uint4 wreg[16];
  for (int c = 0; c < 6; ++c) {
    for (int p = tid; p < 4096; p += 384) {
      int row = p >> 6, cp = p & 63;
      const float* wr = whh + ((size_t)(c * 64 + row)) * 128 + 2 * cp;
      f16 h0 = (f16)wr[0], h1 = (f16)wr[1];
      uint32_t u = (uint32_t)__builtin_bit_cast(unsigned short, h0) |
                   ((uint32_t)__builtin_bit_cast(unsigned short, h1) << 16);
      swc[row][cp] = u;
    }
    __syncthreads();
    if (myc == c) {
#pragma unroll
      for (int q = 0; q < 16; ++q) wreg[q] = *(const uint4*)&swc[lr][q * 4];
    }
    __syncthreads();
  }
  if (tid < 128) hf[tid] = 0.f;
  if (tid < 64) hp[tid] = 0u;
  float bias_g = bhh[tid];
  __syncthreads();
  for (int t = 0; t < Ln; ++t) {
    float grv = 0.f, gzv = 0.f, gnv = 0.f, hprev = 0.f;
    if (tid < 128) {
      const float* gp = gi + ((size_t)t * Bn + n) * 384;
      grv = gp[tid]; gzv = gp[128 + tid]; gnv = gp[256 + tid];
      hprev = hf[tid];
    }
    float acc = bias_g;
#pragma unroll
    for (int q = 0; q < 16; ++q) {
      uint4 h4 = *(const uint4*)&hp[q * 4];
      uint4 w4 = wreg[q];
      const uint32_t hu[4] = {h4.x, h4.y, h4.z, h4.w};
      const uint32_t wu[4] = {w4.x, w4.y, w4.z, w4.w};
#pragma unroll
      for (int e = 0; e < 4; ++e) {
        f16x2 wvp = __builtin_bit_cast(f16x2, wu[e]);
        f16x2 hvp = __builtin_bit_cast(f16x2, hu[e]);
        acc = fmaf((float)wvp.x, (float)hvp.x, acc);
        acc = fmaf((float)wvp.y, (float)hvp.y, acc);
      }
    }
    ghb[tid] = acc;
    __syncthreads();
    if (tid < 128) {
      float rg = sigmf(grv + ghb[tid]);
      float zg = sigmf(gzv + ghb[128 + tid]);
      float ng = tanhf(gnv + rg * ghb[256 + tid]);
      float hnew = (1.f - zg) * ng + zg * hprev;
      hf[tid] = hnew;
      float other = __shfl_xor(hnew, 1, 64);
      if (!(tid & 1)) {
        f16 a = (f16)hnew, bq = (f16)other;
        hp[tid >> 1] = (uint32_t)__builtin_bit_cast(unsigned short, a) |
                       ((uint32_t)__builtin_bit_cast(unsigned short, bq) << 16);
      }
    }
    __syncthreads();
  }
  if (tid < 128) hout[(size_t)n * 128 + tid] = hf[tid];
}

// ================= skip-GRU input gemm =================
__global__ __launch_bounds__(256) void gis_k(const float* __restrict__ cc, const float* __restrict__ wih,
                                             const float* __restrict__ bih, float* __restrict__ gi) {
  __shared__ float sx[24 * 128];
  int t = blockIdx.x, b = blockIdx.y;
  int tid = threadIdx.x;
  for (int idx = tid; idx < 24 * 128; idx += 256) {
    int sk = idx >> 7, i = idx & 127;
    int l = 19 + t * 24 + sk;
    sx[idx] = cc[((size_t)l * Bn + b) * HIDCn + i];
  }
  __syncthreads();
  for (int idx = tid; idx < 576; idx += 256) {
    int sk = idx / 24, g = idx - sk * 24;
    float a = bih[g];
    for (int i = 0; i < 128; ++i) a = fmaf(sx[sk * 128 + i], wih[g * 128 + i], a);
    gi[((size_t)t * (Bn * SKIPn) + b * 24 + sk) * 24 + g] = a;
  }
}

// ================= skip-GRU recurrent =================
__global__ __launch_bounds__(256) void grus_k(const float* __restrict__ gi, const float* __restrict__ whh,
                                              const float* __restrict__ bhh, float* __restrict__ hout) {
  __shared__ float sw[24 * 8];
  __shared__ float sb[24];
  int tid = threadIdx.x;
  int n = blockIdx.x * 256 + tid;
  if (tid < 192) sw[tid] = whh[tid];
  if (tid < 24) sb[tid] = bhh[tid];
  __syncthreads();
  float h[8];
#pragma unroll
  for (int jj = 0; jj < 8; ++jj) h[jj] = 0.f;
  for (int t = 0; t < PTn; ++t) {
    const float* gir = gi + ((size_t)t * (Bn * SKIPn) + n) * 24;
    float gh[24];
#pragma unroll
    for (int g = 0; g < 24; ++g) {
      float a = sb[g];
#pragma unroll
      for (int jj = 0; jj < 8; ++jj) a = fmaf(sw[g * 8 + jj], h[jj], a);
      gh[g] = a;
    }
#pragma unroll
    for (int jj = 0; jj < 8; ++jj) {
      float rg = sigmf(gir[jj] + gh[jj]);
      float zg = sigmf(gir[8 + jj] + gh[8 + jj]);
      float ng = tanhf(gir[16 + jj] + rg * gh[16 + jj]);
      h[jj] = (1.f - zg) * ng + zg * h[jj];
    }
  }
#pragma unroll
  for (int jj = 0; jj < 8; ++jj) hout[(size_t)n * 8 + jj] = h[jj];
}

// ================= final linear + highway =================
__global__ __launch_bounds__(384) void final_k(const float* __restrict__ h1, const float* __restrict__ hsb,
                                               const float* __restrict__ lw, const float* __restrict__ lb,
                                               const float* __restrict__ xr, const float* __restrict__ hww,
                                               const float* __restrict__ hwb, float* __restrict__ out) {
  __shared__ float sr[320];
  __shared__ float shw[24];
  int b = blockIdx.x;
  int tid = threadIdx.x;
  if (tid < 128) sr[tid] = h1[(size_t)b * 128 + tid];
  else if (tid < 320) sr[tid] = hsb[(size_t)b * 192 + (tid - 128)];
  if (tid >= 320 && tid < 344) shw[tid - 320] = hww[tid - 320];
  __syncthreads();
  int m = tid;
  if (m >= Mn) return;
  float a = lb[m];
  const float* wr = lw + (size_t)m * 320;
  for (int c = 0; c < 320; ++c) a = fmaf(sr[c], wr[c], a);
  float z = hwb[0];
  const float* xrr = xr + ((size_t)b * Pn + (Pn - HWn)) * Mn + m;
#pragma unroll
  for (int k = 0; k < HWn; ++k) z = fmaf(xrr[(size_t)k * Mn], shw[k], z);
  out[(size_t)b * Mn + m] = a + z;
}

extern "C" void kernel_launch(void* const* d_in, const int* in_sizes, int n_in,
                              void* d_out, int out_size, void* d_ws, size_t ws_size,
                              hipStream_t stream) {
  const float* x = (const float*)d_in[0];
  const float* tw1 = (const float*)d_in[1];
  const float* tb1 = (const float*)d_in[2];
  const float* tw2 = (const float*)d_in[3];
  const float* tb2 = (const float*)d_in[4];
  const float* c1w = (const float*)d_in[5];
  const float* c1b = (const float*)d_in[6];
  const float* g1wih = (const float*)d_in[7];
  const float* g1whh = (const float*)d_in[8];
  const float* g1bih = (const float*)d_in[9];
  const float* g1bhh = (const float*)d_in[10];
  const float* gswih = (const float*)d_in[11];
  const float* gswhh = (const float*)d_in[12];
  const float* gsbih = (const float*)d_in[13];
  const float* gsbhh = (const float*)d_in[14];
  const float* l1w = (const float*)d_in[15];
  const float* l1b = (const float*)d_in[16];
  const float* hww = (const float*)d_in[17];
  const float* hwb = (const float*)d_in[18];
  float* out = (float*)d_out;

  // ---------- workspace plan (~214 MB) ----------
  const size_t Ah = 17891328ull, Bh = 17891328ull, Ch = 17203200ull;  // halves per plane
  f16* Aq = (f16*)d_ws;
  f16* Bq = Aq + Ah;
  f16* Cq = Bq + Bh;
  f16* Wl1 = Cq + Ch;                      // 16*5*21*6144 = 10,321,920 halves
  f16* Wl2 = Wl1 + 10321920ull;            // 16*3*21*6144 = 6,193,152 halves
  float* c1wr = (float*)(Wl2 + 6193152ull);
  float* giA = c1wr + 246528ull;           // 18,382,848 floats
  float* h1 = giA + 18382848ull;
  float* hsb = h1 + (size_t)Bn * HIDRn;
  float* gis = hsb + (size_t)Bn * SKIPn * HIDSn;
  // post-tree aliases
  float* XR = (float*)Bq;                  // 63.1 MB spanning B + part of C
  float* Cc = (float*)Aq;                  // 24.5 MB in A (EU-L2 consumed by combine)

  // region schedule (validated round 3): per level {EO, S1, CD, S3, EU}
  f16* EO[3] = {Aq, Aq, Bq};
  f16* S1[3] = {Bq, Cq, Aq};
  f16* CD[3] = {Cq, Bq, Cq};
  f16* S3[3] = {Aq, Aq, Bq};
  f16* EU[3] = {Bq, Cq, Aq};
  const int WC0[3] = {0, 1, 2}, WC1[3] = {0, 3, 1}, WC2[3] = {0, 0, 1};

  repack_t<<<dim3(4, 61), 256, 0, stream>>>(c1w, c1wr, 128, 1926);

  for (int L = 0; L < 3; ++L) {
    int NL = 1 << L;
    int Th = 96 >> L;
    int Z = 2 * NL;
    long zsEO = (long)Bn * Th * Mp;
    long zsS1 = (long)Bn * (Th + 2) * Mp;
    repack_w<<<dim3(24, 5 * 21, NL * 4), 256, 0, stream>>>(tw1, Wl1, 5, WC0[L], WC1[L], WC2[L]);
    repack_w<<<dim3(24, 3 * 21, NL * 4), 256, 0, stream>>>(tw2, Wl2, 3, WC0[L], WC1[L], WC2[L]);
    if (L == 0)
      deint_k<<<dim3(Bn, Th, 2), 256, 0, stream>>>(x, nullptr, 0, EO[0], Th);
    else
      deint_k<<<dim3(Bn, Th, Z), 256, 0, stream>>>(nullptr, EU[L - 1], 2 * Th, EO[L], Th);
    int ty1 = (Th + 2 + 31) / 32, ty2 = (Th + 31) / 32;
    conv_mfma<5, 0><<<dim3(64, ty1, Z), 512, 0, stream>>>(
        EO[L], zsEO, Th, Wl1, WC0[L], WC1[L], WC2[L], 0, tb1,
        nullptr, 0, S1[L], zsS1, Th + 2);
    conv_mfma<3, 1><<<dim3(64, ty2, Z), 512, 0, stream>>>(
        S1[L], zsS1, Th + 2, Wl2, WC0[L], WC1[L], WC2[L], 0, tb2,
        EO[L], zsEO, CD[L], zsEO, Th);
    conv_mfma<5, 0><<<dim3(64, ty1, Z), 512, 0, stream>>>(
        CD[L], zsEO, Th, Wl1, WC0[L], WC1[L], WC2[L], 2, tb1,
        nullptr, 0, S3[L], zsS1, Th + 2);
    conv_mfma<3, 2><<<dim3(64, ty2, Z), 512, 0, stream>>>(
        S3[L], zsS1, Th + 2, Wl2, WC0[L], WC1[L], WC2[L], 2, tb2,
        CD[L], zsEO, EU[L], zsEO, Th);
  }

  combine_k<<<dim3(Bn, Pn), 256, 0, stream>>>(x, EU[2], XR);

  conv2d_k<<<dim3(Bn, 2, (Ln + 15) / 16), 256, 0, stream>>>(XR, c1wr, c1b, Cc);
  gemm_gi<<<dim3((Ln * Bn) / 64, 384 / 64), 256, 0, stream>>>(Cc, g1wih, g1bih, giA);
  gru1_k<<<dim3(Bn), 384, 0, stream>>>(giA, g1whh, g1bhh, h1);
  gis_k<<<dim3(PTn, Bn), 256, 0, stream>>>(Cc, gswih, gsbih, gis);
  grus_k<<<dim3((Bn * SKIPn) / 256), 256, 0, stream>>>(gis, gswhh, gsbhh, hsb);
  final_k<<<dim3(Bn), 384, 0, stream>>>(h1, hsb, l1w, l1b, XR, hww, hwb, out);
}